// Round 1
// baseline (432.399 us; speedup 1.0000x reference)
//
#include <hip/hip_runtime.h>
#include <stdint.h>

#define B_ 2
#define T_ 4096
#define D_ 512
#define H_ 8
#define DH_ 64

typedef __bf16 bf16;
typedef __bf16 bf16x4_t __attribute__((ext_vector_type(4)));
typedef __bf16 bf16x8_t __attribute__((ext_vector_type(8)));
typedef float f32x4 __attribute__((ext_vector_type(4)));
typedef uint32_t u32;

static constexpr float QSCALE = 0.18033688011112042f;   // log2(e)/8  (folded into Wq, bq)
static constexpr float NEGBIG = -1.4426950408889634e9f; // -1e9 * log2(e)

__device__ __forceinline__ void async16(void* lds, const void* g) {
  __builtin_amdgcn_global_load_lds(
      (const __attribute__((address_space(1))) void*)g,
      (__attribute__((address_space(3))) void*)lds, 16, 0, 0);
}

// ---------------------------------------------------------------- prep ----
// blocks [0,4096): x f32 -> bf16
// blocks [4096,8192): Wq/Wk/Wv -> WTall[n][k] bf16 (Wq pre-scaled), Wo -> WoT[n][k]
// blocks [8192,10240): mask (int32/uint8 auto-detect) -> bitmask words
__global__ __launch_bounds__(256) void prep_kernel(
    const float* __restrict__ x,
    const float* __restrict__ Wq, const float* __restrict__ Wk,
    const float* __restrict__ Wv, const float* __restrict__ Wo,
    const void* __restrict__ maskp,
    bf16* __restrict__ xb, bf16* __restrict__ WTall, bf16* __restrict__ WoT,
    u32* __restrict__ bmask)
{
  int bid = blockIdx.x;
  int tid = threadIdx.x;
  if (bid < 4096) {
    int idx = bid * 256 + tid;            // 1,048,576 float4s = 4,194,304 floats
    const float4* xf = (const float4*)x;
    float4 v = xf[idx];
    bf16x4_t o;
    o[0] = (bf16)v.x; o[1] = (bf16)v.y; o[2] = (bf16)v.z; o[3] = (bf16)v.w;
    ((bf16x4_t*)xb)[idx] = o;
  } else if (bid < 8192) {
    int gid = (bid - 4096) * 256 + tid;   // 1,048,576
    int sel = gid >> 18;                  // 0..3
    int idx = gid & 262143;
    int n = idx >> 9, k = idx & 511;
    if (sel < 3) {
      const float* W = (sel == 0) ? Wq : (sel == 1) ? Wk : Wv;
      float v = W[k * 512 + n];
      if (sel == 0) v *= QSCALE;
      WTall[gid] = (bf16)v;               // WTall[(sel*512+n)*512 + k]
    } else {
      WoT[idx] = (bf16)Wo[k * 512 + n];
    }
  } else {
    int wid = (bid - 8192) * 256 + tid;   // 524,288 words (4096 rows x 128)
    const uint8_t* m8 = (const uint8_t*)maskp;
    // dtype probe: int32 0/1 values have byte(4i+1)==0 always; random bools don't
    bool u8mode = (__ballot(m8[4 * (tid & 63) + 1] != 0) != 0ull);
    int row = wid >> 7, wcol = wid & 127;
    size_t off = (size_t)row * 4096 + (size_t)wcol * 32;
    u32 w = 0;
    if (u8mode) {
      const uint4* p = (const uint4*)(m8 + off);
      uint4 a = p[0], b = p[1];
      u32 ws[8] = {a.x, a.y, a.z, a.w, b.x, b.y, b.z, b.w};
      #pragma unroll
      for (int j = 0; j < 32; ++j)
        if ((ws[j >> 2] >> ((j & 3) * 8)) & 0xffu) w |= (1u << j);
    } else {
      const uint4* p = (const uint4*)((const u32*)maskp + off);
      #pragma unroll
      for (int q = 0; q < 8; ++q) {
        uint4 a = p[q];
        if (a.x) w |= 1u << (q * 4 + 0);
        if (a.y) w |= 1u << (q * 4 + 1);
        if (a.z) w |= 1u << (q * 4 + 2);
        if (a.w) w |= 1u << (q * 4 + 3);
      }
    }
    bmask[wid] = w;
  }
}

// ---------------------------------------------------------- QKV GEMM -------
// C[8192 x 1536] = xb @ [Wq|Wk|Wv]^T(+bias); Q,K -> (B,H,T,64); V -> (B,H,64,T)
__global__ __launch_bounds__(256) void qkv_kernel(
    const bf16* __restrict__ xb, const bf16* __restrict__ WTall,
    const float* __restrict__ bq, const float* __restrict__ bk,
    const float* __restrict__ bv,
    bf16* __restrict__ Qb, bf16* __restrict__ Kb, bf16* __restrict__ Vtb)
{
  __shared__ char smem[16384];
  char* smX = smem;
  char* smW = smem + 8192;
  int tid = threadIdx.x;
  int lane = tid & 63, wave = tid >> 6;
  int lo = lane & 15, quad = lane >> 4;
  int wr = wave >> 1, wc = wave & 1;
  int bm = blockIdx.x * 64;
  int bn = blockIdx.y * 64;
  f32x4 acc[2][2] = {};
  for (int kc = 0; kc < 8; ++kc) {
    __syncthreads();
    for (int s = tid; s < 512; s += 256) {
      int row = s >> 3, slot = s & 7, cg = slot ^ (row & 7);
      async16(smX + s * 16, xb + (size_t)(bm + row) * 512 + kc * 64 + cg * 8);
      async16(smW + s * 16, WTall + (size_t)(bn + row) * 512 + kc * 64 + cg * 8);
    }
    __syncthreads();
    #pragma unroll
    for (int ks = 0; ks < 2; ++ks) {
      bf16x8_t a[2], b[2];
      #pragma unroll
      for (int mt = 0; mt < 2; ++mt) {
        int row = wr * 32 + mt * 16 + lo;
        int ch = (ks * 4 + quad) ^ (row & 7);
        a[mt] = *(const bf16x8_t*)(smX + row * 128 + ch * 16);
      }
      #pragma unroll
      for (int nt = 0; nt < 2; ++nt) {
        int row = wc * 32 + nt * 16 + lo;
        int ch = (ks * 4 + quad) ^ (row & 7);
        b[nt] = *(const bf16x8_t*)(smW + row * 128 + ch * 16);
      }
      #pragma unroll
      for (int mt = 0; mt < 2; ++mt)
        #pragma unroll
        for (int nt = 0; nt < 2; ++nt)
          acc[mt][nt] = __builtin_amdgcn_mfma_f32_16x16x32_bf16(
              a[mt], b[nt], acc[mt][nt], 0, 0, 0);
    }
  }
  int sel = bn >> 9;   // 0=Q 1=K 2=V
  #pragma unroll
  for (int mt = 0; mt < 2; ++mt) {
    #pragma unroll
    for (int nt = 0; nt < 2; ++nt) {
      int n_g = bn + wc * 32 + nt * 16 + lo;
      int n0 = n_g & 511;
      int h = n0 >> 6, dh = n0 & 63;
      int m0 = bm + wr * 32 + mt * 16 + quad * 4;
      int b_ = m0 >> 12;
      int t0 = m0 & 4095;
      float bias = (sel == 0) ? QSCALE * bq[n0] : (sel == 1) ? bk[n0] : bv[n0];
      if (sel < 2) {
        bf16* dst = (sel == 0 ? Qb : Kb) + (size_t)(b_ * H_ + h) * T_ * DH_ + dh;
        #pragma unroll
        for (int r = 0; r < 4; ++r)
          dst[(size_t)(t0 + r) * 64] = (bf16)(acc[mt][nt][r] + bias);
      } else {
        bf16x4_t v;
        #pragma unroll
        for (int r = 0; r < 4; ++r) v[r] = (bf16)(acc[mt][nt][r] + bias);
        *(bf16x4_t*)(Vtb + ((size_t)(b_ * H_ + h) * DH_ + dh) * T_ + t0) = v;
      }
    }
  }
}

// ------------------------------------------------------ flash attention ----
// one WG per (b,h, 64-row q-tile); 4 waves x 16 rows; online softmax per row
__global__ __launch_bounds__(256) void attn_kernel(
    const bf16* __restrict__ Qb, const bf16* __restrict__ Kb,
    const bf16* __restrict__ Vtb, const u32* __restrict__ bmask,
    bf16* __restrict__ Obuf)
{
  __shared__ char smem[25088]; // 8K Q/P + 8K K + 8K Vt + 512B mask words
  char* smQP = smem;
  char* smK = smem + 8192;
  char* smV = smem + 16384;
  u32* smM = (u32*)(smem + 24576);
  int tid = threadIdx.x;
  int lane = tid & 63, wave = tid >> 6;
  int lo = lane & 15, quad = lane >> 4;
  int bh = blockIdx.x >> 6;
  int qbase = (blockIdx.x & 63) * 64;

  const bf16* Qg = Qb + (size_t)bh * T_ * DH_ + (size_t)qbase * DH_;
  for (int s = tid; s < 512; s += 256) {
    int row = s >> 3, slot = s & 7, cg = slot ^ (row & 7);
    async16(smQP + s * 16, Qg + row * 64 + cg * 8);
  }
  __syncthreads();
  bf16x8_t qf[2];
  #pragma unroll
  for (int ks = 0; ks < 2; ++ks) {
    int row = wave * 16 + lo;
    int ch = (ks * 4 + quad) ^ (row & 7);
    qf[ks] = *(const bf16x8_t*)(smQP + row * 128 + ch * 16);
  }
  f32x4 Oa[4] = {};
  float mst[4], lst[4];
  #pragma unroll
  for (int r = 0; r < 4; ++r) { mst[r] = -3.0e38f; lst[r] = 0.f; }

  const bf16* Kg = Kb + (size_t)bh * T_ * DH_;
  const bf16* Vg = Vtb + (size_t)bh * DH_ * T_;
  const u32* mg = bmask + (size_t)qbase * 128;

  for (int kc = 0; kc < 64; ++kc) {
    __syncthreads();
    for (int s = tid; s < 512; s += 256) {
      int row = s >> 3, slot = s & 7, cg = slot ^ (row & 7);
      async16(smK + s * 16, Kg + (size_t)(kc * 64 + row) * 64 + cg * 8);
      async16(smV + s * 16, Vg + (size_t)row * T_ + kc * 64 + cg * 8);
    }
    if (tid < 128) {
      int r2 = tid >> 1, w = tid & 1;
      smM[r2 * 2 + w] = mg[(size_t)r2 * 128 + kc * 2 + w];
    }
    __syncthreads();
    // S = (scaled Q) K^T : 16 rows x 64 keys per wave
    f32x4 S[4] = {};
    #pragma unroll
    for (int ks = 0; ks < 2; ++ks) {
      #pragma unroll
      for (int nt = 0; nt < 4; ++nt) {
        int krow = nt * 16 + lo;
        int ch = (ks * 4 + quad) ^ (krow & 7);
        bf16x8_t kf = *(const bf16x8_t*)(smK + krow * 128 + ch * 16);
        S[nt] = __builtin_amdgcn_mfma_f32_16x16x32_bf16(qf[ks], kf, S[nt], 0, 0, 0);
      }
    }
    // mask + online softmax; rows are wave-private
    #pragma unroll
    for (int r = 0; r < 4; ++r) {
      int rl = wave * 16 + quad * 4 + r;
      u32 w0 = smM[rl * 2 + 0];
      u32 w1 = smM[rl * 2 + 1];
      float s0 = ((w0 >> lo) & 1u) ? S[0][r] : NEGBIG;
      float s1 = ((w0 >> (16 + lo)) & 1u) ? S[1][r] : NEGBIG;
      float s2 = ((w1 >> lo) & 1u) ? S[2][r] : NEGBIG;
      float s3 = ((w1 >> (16 + lo)) & 1u) ? S[3][r] : NEGBIG;
      float mx = fmaxf(fmaxf(s0, s1), fmaxf(s2, s3));
      mx = fmaxf(mx, __shfl_xor(mx, 1));
      mx = fmaxf(mx, __shfl_xor(mx, 2));
      mx = fmaxf(mx, __shfl_xor(mx, 4));
      mx = fmaxf(mx, __shfl_xor(mx, 8));
      float mnew = fmaxf(mst[r], mx);
      float alpha = __builtin_amdgcn_exp2f(mst[r] - mnew);
      mst[r] = mnew;
      float p0 = __builtin_amdgcn_exp2f(s0 - mnew);
      float p1 = __builtin_amdgcn_exp2f(s1 - mnew);
      float p2 = __builtin_amdgcn_exp2f(s2 - mnew);
      float p3 = __builtin_amdgcn_exp2f(s3 - mnew);
      float rs = (p0 + p1) + (p2 + p3);
      rs += __shfl_xor(rs, 1);
      rs += __shfl_xor(rs, 2);
      rs += __shfl_xor(rs, 4);
      rs += __shfl_xor(rs, 8);
      lst[r] = lst[r] * alpha + rs;
      #pragma unroll
      for (int nt = 0; nt < 4; ++nt) Oa[nt][r] *= alpha;
      S[0][r] = p0; S[1][r] = p1; S[2][r] = p2; S[3][r] = p3;
    }
    // P -> LDS (C-layout -> A-layout round trip); wave-private rows
    #pragma unroll
    for (int nt = 0; nt < 4; ++nt) {
      int col = nt * 16 + lo;
      #pragma unroll
      for (int r = 0; r < 4; ++r) {
        int prow = wave * 16 + quad * 4 + r;
        int ch = (col >> 3) ^ (prow & 7);
        *(bf16*)(smQP + prow * 128 + ch * 16 + (col & 7) * 2) = (bf16)S[nt][r];
      }
    }
    // O += P V  (wave reads only its own P rows -> no extra barrier needed)
    #pragma unroll
    for (int ks = 0; ks < 2; ++ks) {
      int prow = wave * 16 + lo;
      int ch = (ks * 4 + quad) ^ (prow & 7);
      bf16x8_t pf = *(const bf16x8_t*)(smQP + prow * 128 + ch * 16);
      #pragma unroll
      for (int nt = 0; nt < 4; ++nt) {
        int vrow = nt * 16 + lo;
        int ch2 = (ks * 4 + quad) ^ (vrow & 7);
        bf16x8_t vf = *(const bf16x8_t*)(smV + vrow * 128 + ch2 * 16);
        Oa[nt] = __builtin_amdgcn_mfma_f32_16x16x32_bf16(pf, vf, Oa[nt], 0, 0, 0);
      }
    }
  }
  bf16* Og = Obuf + (size_t)bh * T_ * DH_;
  #pragma unroll
  for (int nt = 0; nt < 4; ++nt) {
    int col = nt * 16 + lo;
    #pragma unroll
    for (int r = 0; r < 4; ++r) {
      int row = qbase + wave * 16 + quad * 4 + r;
      Og[(size_t)row * 64 + col] = (bf16)(Oa[nt][r] / lst[r]);
    }
  }
}

// ------------------------------------------------------ output proj --------
__global__ __launch_bounds__(256) void proj_kernel(
    const bf16* __restrict__ Obuf, const bf16* __restrict__ WoT,
    const float* __restrict__ bo, float* __restrict__ out)
{
  __shared__ char smem[16384];
  char* smA = smem;
  char* smW = smem + 8192;
  int tid = threadIdx.x;
  int lane = tid & 63, wave = tid >> 6;
  int lo = lane & 15, quad = lane >> 4;
  int wr = wave >> 1, wc = wave & 1;
  int bm = blockIdx.x * 64;
  int bn = blockIdx.y * 64;
  int b_ = bm >> 12, trow = bm & 4095;
  f32x4 acc[2][2] = {};
  for (int kc = 0; kc < 8; ++kc) {
    __syncthreads();
    const bf16* Ag = Obuf + ((size_t)(b_ * H_ + kc) * T_ + trow) * DH_;
    for (int s = tid; s < 512; s += 256) {
      int row = s >> 3, slot = s & 7, cg = slot ^ (row & 7);
      async16(smA + s * 16, Ag + row * 64 + cg * 8);
      async16(smW + s * 16, WoT + (size_t)(bn + row) * 512 + kc * 64 + cg * 8);
    }
    __syncthreads();
    #pragma unroll
    for (int ks = 0; ks < 2; ++ks) {
      bf16x8_t a[2], b[2];
      #pragma unroll
      for (int mt = 0; mt < 2; ++mt) {
        int row = wr * 32 + mt * 16 + lo;
        int ch = (ks * 4 + quad) ^ (row & 7);
        a[mt] = *(const bf16x8_t*)(smA + row * 128 + ch * 16);
      }
      #pragma unroll
      for (int nt = 0; nt < 2; ++nt) {
        int row = wc * 32 + nt * 16 + lo;
        int ch = (ks * 4 + quad) ^ (row & 7);
        b[nt] = *(const bf16x8_t*)(smW + row * 128 + ch * 16);
      }
      #pragma unroll
      for (int mt = 0; mt < 2; ++mt)
        #pragma unroll
        for (int nt = 0; nt < 2; ++nt)
          acc[mt][nt] = __builtin_amdgcn_mfma_f32_16x16x32_bf16(
              a[mt], b[nt], acc[mt][nt], 0, 0, 0);
    }
  }
  #pragma unroll
  for (int mt = 0; mt < 2; ++mt) {
    #pragma unroll
    for (int nt = 0; nt < 2; ++nt) {
      int n_g = bn + wc * 32 + nt * 16 + lo;
      int m0 = bm + wr * 32 + mt * 16 + quad * 4;
      float bias = bo[n_g];
      #pragma unroll
      for (int r = 0; r < 4; ++r)
        out[(size_t)(m0 + r) * 512 + n_g] = acc[mt][nt][r] + bias;
    }
  }
}

// --------------------------------------------------------------- launch ----
extern "C" void kernel_launch(void* const* d_in, const int* in_sizes, int n_in,
                              void* d_out, int out_size, void* d_ws, size_t ws_size,
                              hipStream_t stream) {
  const float* x  = (const float*)d_in[0];
  const float* Wq = (const float*)d_in[1];
  const float* bq = (const float*)d_in[2];
  const float* Wk = (const float*)d_in[3];
  const float* bk = (const float*)d_in[4];
  const float* Wv = (const float*)d_in[5];
  const float* bv = (const float*)d_in[6];
  const float* Wo = (const float*)d_in[7];
  const float* bo = (const float*)d_in[8];
  const void* maskp = d_in[9];
  float* out = (float*)d_out;

  char* w = (char*)d_ws;
  bf16* xb    = (bf16*)(w);              //  8,388,608 B
  bf16* WTall = (bf16*)(w + 8388608);    //  1,572,864 B
  bf16* WoT   = (bf16*)(w + 9961472);    //    524,288 B
  bf16* Qb    = (bf16*)(w + 10485760);   //  8,388,608 B
  bf16* Kb    = (bf16*)(w + 18874368);   //  8,388,608 B
  bf16* Vtb   = (bf16*)(w + 27262976);   //  8,388,608 B  (B,H,DH,T)
  bf16* Obuf  = (bf16*)(w + 35651584);   //  8,388,608 B
  u32*  bmask = (u32*)(w + 44040192);    //  2,097,152 B

  prep_kernel<<<10240, 256, 0, stream>>>(x, Wq, Wk, Wv, Wo, maskp,
                                         xb, WTall, WoT, bmask);
  qkv_kernel<<<dim3(128, 24), 256, 0, stream>>>(xb, WTall, bq, bk, bv,
                                                Qb, Kb, Vtb);
  attn_kernel<<<1024, 256, 0, stream>>>(Qb, Kb, Vtb, bmask, Obuf);
  proj_kernel<<<dim3(128, 8), 256, 0, stream>>>(Obuf, WoT, bo, out);
}

// Round 2
// 305.504 us; speedup vs baseline: 1.4154x; 1.4154x over previous
//
#include <hip/hip_runtime.h>
#include <stdint.h>

#define B_ 2
#define T_ 4096
#define D_ 512
#define H_ 8
#define DH_ 64

typedef __bf16 bf16;
typedef __bf16 bf16x4_t __attribute__((ext_vector_type(4)));
typedef __bf16 bf16x8_t __attribute__((ext_vector_type(8)));
typedef float f32x4 __attribute__((ext_vector_type(4)));
typedef uint32_t u32;

static constexpr float QSCALE = 0.18033688011112042f;   // log2(e)/8 (folded into Wq,bq)

__device__ __forceinline__ void async16(void* lds, const void* g) {
  __builtin_amdgcn_global_load_lds(
      (const __attribute__((address_space(1))) void*)g,
      (__attribute__((address_space(3))) void*)lds, 16, 0, 0);
}

// ---------------------------------------------------------------- prep ----
// blocks [0,4096): x f32 -> bf16
// blocks [4096,8192): Wq/Wk/Wv -> WTall[n][k] bf16 (Wq pre-scaled), Wo -> WoT[n][k]
// blocks [8192,10240): mask -> bitmask, kc-major layout:
//   bm2[((row>>6)*64 + kc)*128 + (row&63)*2 + w]  covers keys kc*64 + w*32 +bit
__global__ __launch_bounds__(256) void prep_kernel(
    const float* __restrict__ x,
    const float* __restrict__ Wq, const float* __restrict__ Wk,
    const float* __restrict__ Wv, const float* __restrict__ Wo,
    const void* __restrict__ maskp,
    bf16* __restrict__ xb, bf16* __restrict__ WTall, bf16* __restrict__ WoT,
    u32* __restrict__ bmask)
{
  int bid = blockIdx.x;
  int tid = threadIdx.x;
  if (bid < 4096) {
    int idx = bid * 256 + tid;
    const float4* xf = (const float4*)x;
    float4 v = xf[idx];
    bf16x4_t o;
    o[0] = (bf16)v.x; o[1] = (bf16)v.y; o[2] = (bf16)v.z; o[3] = (bf16)v.w;
    ((bf16x4_t*)xb)[idx] = o;
  } else if (bid < 8192) {
    int gid = (bid - 4096) * 256 + tid;
    int sel = gid >> 18;
    int idx = gid & 262143;
    int n = idx >> 9, k = idx & 511;
    if (sel < 3) {
      const float* W = (sel == 0) ? Wq : (sel == 1) ? Wk : Wv;
      float v = W[k * 512 + n];
      if (sel == 0) v *= QSCALE;
      WTall[gid] = (bf16)v;
    } else {
      WoT[idx] = (bf16)Wo[k * 512 + n];
    }
  } else {
    int wid = (bid - 8192) * 256 + tid;   // 524,288 words
    const uint8_t* m8 = (const uint8_t*)maskp;
    bool u8mode = (__ballot(m8[4 * (tid & 63) + 1] != 0) != 0ull);
    int row = wid >> 7, wcol = wid & 127;
    size_t off = (size_t)row * 4096 + (size_t)wcol * 32;
    u32 w = 0;
    if (u8mode) {
      const uint4* p = (const uint4*)(m8 + off);
      uint4 a = p[0], b = p[1];
      u32 ws[8] = {a.x, a.y, a.z, a.w, b.x, b.y, b.z, b.w};
      #pragma unroll
      for (int j = 0; j < 32; ++j)
        if ((ws[j >> 2] >> ((j & 3) * 8)) & 0xffu) w |= (1u << j);
    } else {
      const uint4* p = (const uint4*)((const u32*)maskp + off);
      #pragma unroll
      for (int q = 0; q < 8; ++q) {
        uint4 a = p[q];
        if (a.x) w |= 1u << (q * 4 + 0);
        if (a.y) w |= 1u << (q * 4 + 1);
        if (a.z) w |= 1u << (q * 4 + 2);
        if (a.w) w |= 1u << (q * 4 + 3);
      }
    }
    bmask[((size_t)(row >> 6) * 64 + (wcol >> 1)) * 128 + (row & 63) * 2 + (wcol & 1)] = w;
  }
}

// ---------------------------------------------------------- QKV GEMM -------
// C[8192 x 1536] = xb @ [Wq|Wk|Wv]^T(+bias); Q,K -> (B,H,T,64); V -> (B,H,64,T)
// V block computed operand-swapped so V^T stores are lane-contiguous.
__global__ __launch_bounds__(256) void qkv_kernel(
    const bf16* __restrict__ xb, const bf16* __restrict__ WTall,
    const float* __restrict__ bq, const float* __restrict__ bk,
    const float* __restrict__ bv,
    bf16* __restrict__ Qb, bf16* __restrict__ Kb, bf16* __restrict__ Vtb)
{
  __shared__ char smem[16384];
  char* smX = smem;
  char* smW = smem + 8192;
  int tid = threadIdx.x;
  int lane = tid & 63, wave = tid >> 6;
  int lo = lane & 15, quad = lane >> 4;
  int wr = wave >> 1, wc = wave & 1;
  int bm = blockIdx.x * 64;
  int bn = blockIdx.y * 64;
  int sel = bn >> 9;   // 0=Q 1=K 2=V
  f32x4 acc[2][2] = {};
  for (int kc = 0; kc < 8; ++kc) {
    __syncthreads();
    for (int s = tid; s < 512; s += 256) {
      int row = s >> 3, slot = s & 7, cg = slot ^ (row & 7);
      async16(smX + s * 16, xb + (size_t)(bm + row) * 512 + kc * 64 + cg * 8);
      async16(smW + s * 16, WTall + (size_t)(bn + row) * 512 + kc * 64 + cg * 8);
    }
    __syncthreads();
    #pragma unroll
    for (int ks = 0; ks < 2; ++ks) {
      bf16x8_t a[2], b[2];
      #pragma unroll
      for (int mt = 0; mt < 2; ++mt) {
        int row = wr * 32 + mt * 16 + lo;
        int ch = (ks * 4 + quad) ^ (row & 7);
        a[mt] = *(const bf16x8_t*)(smX + row * 128 + ch * 16);
      }
      #pragma unroll
      for (int nt = 0; nt < 2; ++nt) {
        int row = wc * 32 + nt * 16 + lo;
        int ch = (ks * 4 + quad) ^ (row & 7);
        b[nt] = *(const bf16x8_t*)(smW + row * 128 + ch * 16);
      }
      if (sel == 2) {
        #pragma unroll
        for (int mt = 0; mt < 2; ++mt)
          #pragma unroll
          for (int nt = 0; nt < 2; ++nt)
            acc[mt][nt] = __builtin_amdgcn_mfma_f32_16x16x32_bf16(
                b[nt], a[mt], acc[mt][nt], 0, 0, 0);   // D rows = W-dim, cols = t
      } else {
        #pragma unroll
        for (int mt = 0; mt < 2; ++mt)
          #pragma unroll
          for (int nt = 0; nt < 2; ++nt)
            acc[mt][nt] = __builtin_amdgcn_mfma_f32_16x16x32_bf16(
                a[mt], b[nt], acc[mt][nt], 0, 0, 0);
      }
    }
  }
  int b_ = bm >> 12;
  if (sel < 2) {
    #pragma unroll
    for (int mt = 0; mt < 2; ++mt) {
      #pragma unroll
      for (int nt = 0; nt < 2; ++nt) {
        int n0 = (bn + wc * 32 + nt * 16 + lo) & 511;
        int h = n0 >> 6, dh = n0 & 63;
        int m0 = bm + wr * 32 + mt * 16 + quad * 4;
        int t0 = m0 & 4095;
        float bias = (sel == 0) ? QSCALE * bq[n0] : bk[n0];
        bf16* dst = (sel == 0 ? Qb : Kb) + (size_t)(b_ * H_ + h) * T_ * DH_ + dh;
        #pragma unroll
        for (int r = 0; r < 4; ++r)
          dst[(size_t)(t0 + r) * 64] = (bf16)(acc[mt][nt][r] + bias);
      }
    }
  } else {
    #pragma unroll
    for (int mt = 0; mt < 2; ++mt) {
      #pragma unroll
      for (int nt = 0; nt < 2; ++nt) {
        int t0 = (bm & 4095) + wr * 32 + mt * 16 + lo;
        #pragma unroll
        for (int r = 0; r < 4; ++r) {
          int n0 = (bn & 511) + wc * 32 + nt * 16 + quad * 4 + r;
          float v = acc[mt][nt][r] + bv[n0];
          Vtb[((size_t)(b_ * H_ + (n0 >> 6)) * DH_ + (n0 & 63)) * T_ + t0] = (bf16)v;
        }
      }
    }
  }
}

// ------------------------------------------------------ flash attention ----
// one WG per (b,h, 64-row q-tile); wave (qh,kh) = 32q x 32k tile.
// Unnormalized softmax (no running max): p = mask ? exp2(s) : 0;
// row sums + O combined across kh wave-pair once at the end.
__global__ __launch_bounds__(256, 4) void attn_kernel(
    const bf16* __restrict__ Qb, const bf16* __restrict__ Kb,
    const bf16* __restrict__ Vtb, const u32* __restrict__ bm2,
    bf16* __restrict__ Obuf)
{
  __shared__ char smem[27648];
  char* smK = smem;            // 8192 (64 key-rows x 128B, xor-swizzled)
  char* smV = smem + 8192;     // 8192 (64 d-rows x 128B, xor-swizzled)
  char* smP = smem + 16384;    // 10240 (4 waves x 32 rows x 80B)
  char* smM = smem + 26624;    // 512
  int tid = threadIdx.x;
  int lane = tid & 63, wave = tid >> 6;
  int lo = lane & 15, quad = lane >> 4;
  int qh = wave & 1, kh = wave >> 1;
  int bh = blockIdx.x >> 6;
  int qt = blockIdx.x & 63;
  int qbase = qt * 64;
  char* smPw = smP + wave * 2560;

  // preload Q A-fragments (loop-invariant)
  const bf16* Qg = Qb + ((size_t)bh * T_ + qbase + qh * 32) * DH_;
  bf16x8_t qf[2][2];
  #pragma unroll
  for (int mt = 0; mt < 2; ++mt)
    #pragma unroll
    for (int ks = 0; ks < 2; ++ks)
      qf[mt][ks] = *(const bf16x8_t*)(Qg + (mt * 16 + lo) * 64 + ks * 32 + quad * 8);

  f32x4 O[2][4] = {};
  float lsum[2][4] = {};

  const bf16* Kg = Kb + (size_t)bh * T_ * DH_;
  const bf16* Vg = Vtb + (size_t)bh * DH_ * T_;
  const u32* mg = bm2 + (size_t)qt * 8192;

  for (int kc = 0; kc < 64; ++kc) {
    __syncthreads();                       // prior compute done: safe to restage
    for (int s = tid; s < 512; s += 256) {
      int row = s >> 3, slot = s & 7, cg = slot ^ (row & 7);
      async16(smK + s * 16, Kg + (size_t)(kc * 64 + row) * 64 + cg * 8);
      async16(smV + s * 16, Vg + (size_t)row * T_ + kc * 64 + cg * 8);
    }
    if (tid < 128) ((u32*)smM)[tid] = mg[kc * 128 + tid];
    __syncthreads();                       // staging visible
    // S = QK^T (32q x 32k per wave)
    f32x4 S[2][2] = {};
    #pragma unroll
    for (int ks = 0; ks < 2; ++ks)
      #pragma unroll
      for (int nt = 0; nt < 2; ++nt) {
        int key = kh * 32 + nt * 16 + lo;
        int ch = (ks * 4 + quad) ^ (key & 7);
        bf16x8_t kf = *(const bf16x8_t*)(smK + key * 128 + ch * 16);
        #pragma unroll
        for (int mt = 0; mt < 2; ++mt)
          S[mt][nt] = __builtin_amdgcn_mfma_f32_16x16x32_bf16(
              qf[mt][ks], kf, S[mt][nt], 0, 0, 0);
      }
    // mask + exp2 + lane-local row partials + P write (wave-private region)
    #pragma unroll
    for (int mt = 0; mt < 2; ++mt)
      #pragma unroll
      for (int r = 0; r < 4; ++r) {
        int q_l = qh * 32 + mt * 16 + quad * 4 + r;
        u32 w = (*(const u32*)(smM + (q_l * 2 + kh) * 4)) >> lo;
        int prow = mt * 16 + quad * 4 + r;
        #pragma unroll
        for (int nt = 0; nt < 2; ++nt) {
          float p = __builtin_amdgcn_exp2f(S[mt][nt][r]);
          p = ((w >> (nt * 16)) & 1u) ? p : 0.0f;
          lsum[mt][r] += p;
          *(bf16*)(smPw + prow * 80 + (nt * 16 + lo) * 2) = (bf16)p;
        }
      }
    // O += P V over this wave's 32 keys (P wave-private: no barrier needed)
    bf16x8_t pf[2];
    #pragma unroll
    for (int mt = 0; mt < 2; ++mt)
      pf[mt] = *(const bf16x8_t*)(smPw + (mt * 16 + lo) * 80 + quad * 16);
    #pragma unroll
    for (int dt = 0; dt < 4; ++dt) {
      int d = dt * 16 + lo;
      int ch = (kh * 4 + quad) ^ (d & 7);
      bf16x8_t vf = *(const bf16x8_t*)(smV + d * 128 + ch * 16);
      #pragma unroll
      for (int mt = 0; mt < 2; ++mt)
        O[mt][dt] = __builtin_amdgcn_mfma_f32_16x16x32_bf16(
            pf[mt], vf, O[mt][dt], 0, 0, 0);
    }
  }
  // ---- epilogue: reduce row sums across 16 col-lanes, combine kh pair ----
  #pragma unroll
  for (int mt = 0; mt < 2; ++mt)
    #pragma unroll
    for (int r = 0; r < 4; ++r) {
      float v = lsum[mt][r];
      v += __shfl_xor(v, 1); v += __shfl_xor(v, 2);
      v += __shfl_xor(v, 4); v += __shfl_xor(v, 8);
      lsum[mt][r] = v;
    }
  __syncthreads();                 // done reading smK/smV: reuse as combine area
  float* smO = (float*)smem;       // 64 rows x 64 cols f32 = 16 KB
  float* smL = (float*)smP;        // 64 floats
  if (kh == 1) {
    #pragma unroll
    for (int mt = 0; mt < 2; ++mt) {
      #pragma unroll
      for (int dt = 0; dt < 4; ++dt)
        #pragma unroll
        for (int r = 0; r < 4; ++r)
          smO[(qh * 32 + mt * 16 + quad * 4 + r) * 64 + dt * 16 + lo] = O[mt][dt][r];
      if (lo == 0)
        #pragma unroll
        for (int r = 0; r < 4; ++r)
          smL[qh * 32 + mt * 16 + quad * 4 + r] = lsum[mt][r];
    }
  }
  __syncthreads();
  if (kh == 0) {
    bf16* Og = Obuf + ((size_t)bh * T_ + qbase + qh * 32) * DH_;
    #pragma unroll
    for (int mt = 0; mt < 2; ++mt) {
      float inv[4];
      #pragma unroll
      for (int r = 0; r < 4; ++r) {
        int row = qh * 32 + mt * 16 + quad * 4 + r;
        inv[r] = 1.0f / (lsum[mt][r] + smL[row]);
      }
      #pragma unroll
      for (int dt = 0; dt < 4; ++dt)
        #pragma unroll
        for (int r = 0; r < 4; ++r) {
          int rl = mt * 16 + quad * 4 + r;
          float o = (O[mt][dt][r] + smO[(qh * 32 + rl) * 64 + dt * 16 + lo]) * inv[r];
          Og[(size_t)rl * 64 + dt * 16 + lo] = (bf16)o;
        }
    }
  }
}

// ------------------------------------------------------ output proj --------
__global__ __launch_bounds__(256) void proj_kernel(
    const bf16* __restrict__ Obuf, const bf16* __restrict__ WoT,
    const float* __restrict__ bo, float* __restrict__ out)
{
  __shared__ char smem[16384];
  char* smA = smem;
  char* smW = smem + 8192;
  int tid = threadIdx.x;
  int lane = tid & 63, wave = tid >> 6;
  int lo = lane & 15, quad = lane >> 4;
  int wr = wave >> 1, wc = wave & 1;
  int bm = blockIdx.x * 64;
  int bn = blockIdx.y * 64;
  int b_ = bm >> 12, trow = bm & 4095;
  f32x4 acc[2][2] = {};
  for (int kc = 0; kc < 8; ++kc) {
    __syncthreads();
    const bf16* Ag = Obuf + ((size_t)(b_ * H_ + kc) * T_ + trow) * DH_;
    for (int s = tid; s < 512; s += 256) {
      int row = s >> 3, slot = s & 7, cg = slot ^ (row & 7);
      async16(smA + s * 16, Ag + row * 64 + cg * 8);
      async16(smW + s * 16, WoT + (size_t)(bn + row) * 512 + kc * 64 + cg * 8);
    }
    __syncthreads();
    #pragma unroll
    for (int ks = 0; ks < 2; ++ks) {
      bf16x8_t a[2], b[2];
      #pragma unroll
      for (int mt = 0; mt < 2; ++mt) {
        int row = wr * 32 + mt * 16 + lo;
        int ch = (ks * 4 + quad) ^ (row & 7);
        a[mt] = *(const bf16x8_t*)(smA + row * 128 + ch * 16);
      }
      #pragma unroll
      for (int nt = 0; nt < 2; ++nt) {
        int row = wc * 32 + nt * 16 + lo;
        int ch = (ks * 4 + quad) ^ (row & 7);
        b[nt] = *(const bf16x8_t*)(smW + row * 128 + ch * 16);
      }
      #pragma unroll
      for (int mt = 0; mt < 2; ++mt)
        #pragma unroll
        for (int nt = 0; nt < 2; ++nt)
          acc[mt][nt] = __builtin_amdgcn_mfma_f32_16x16x32_bf16(
              a[mt], b[nt], acc[mt][nt], 0, 0, 0);
    }
  }
  #pragma unroll
  for (int mt = 0; mt < 2; ++mt) {
    #pragma unroll
    for (int nt = 0; nt < 2; ++nt) {
      int n_g = bn + wc * 32 + nt * 16 + lo;
      int m0 = bm + wr * 32 + mt * 16 + quad * 4;
      float bias = bo[n_g];
      #pragma unroll
      for (int r = 0; r < 4; ++r)
        out[(size_t)(m0 + r) * 512 + n_g] = acc[mt][nt][r] + bias;
    }
  }
}

// --------------------------------------------------------------- launch ----
extern "C" void kernel_launch(void* const* d_in, const int* in_sizes, int n_in,
                              void* d_out, int out_size, void* d_ws, size_t ws_size,
                              hipStream_t stream) {
  const float* x  = (const float*)d_in[0];
  const float* Wq = (const float*)d_in[1];
  const float* bq = (const float*)d_in[2];
  const float* Wk = (const float*)d_in[3];
  const float* bk = (const float*)d_in[4];
  const float* Wv = (const float*)d_in[5];
  const float* bv = (const float*)d_in[6];
  const float* Wo = (const float*)d_in[7];
  const float* bo = (const float*)d_in[8];
  const void* maskp = d_in[9];
  float* out = (float*)d_out;

  char* w = (char*)d_ws;
  bf16* xb    = (bf16*)(w);              //  8,388,608 B
  bf16* WTall = (bf16*)(w + 8388608);    //  1,572,864 B
  bf16* WoT   = (bf16*)(w + 9961472);    //    524,288 B
  bf16* Qb    = (bf16*)(w + 10485760);   //  8,388,608 B
  bf16* Kb    = (bf16*)(w + 18874368);   //  8,388,608 B
  bf16* Vtb   = (bf16*)(w + 27262976);   //  8,388,608 B  (B,H,DH,T)
  bf16* Obuf  = (bf16*)(w + 35651584);   //  8,388,608 B
  u32*  bmask = (u32*)(w + 44040192);    //  2,097,152 B

  prep_kernel<<<10240, 256, 0, stream>>>(x, Wq, Wk, Wv, Wo, maskp,
                                         xb, WTall, WoT, bmask);
  qkv_kernel<<<dim3(128, 24), 256, 0, stream>>>(xb, WTall, bq, bk, bv,
                                                Qb, Kb, Vtb);
  attn_kernel<<<1024, 256, 0, stream>>>(Qb, Kb, Vtb, bmask, Obuf);
  proj_kernel<<<dim3(128, 8), 256, 0, stream>>>(Obuf, WoT, bo, out);
}

// Round 3
// 301.977 us; speedup vs baseline: 1.4319x; 1.0117x over previous
//
#include <hip/hip_runtime.h>
#include <stdint.h>

#define B_ 2
#define T_ 4096
#define D_ 512
#define H_ 8
#define DH_ 64

typedef __bf16 bf16;
typedef __bf16 bf16x4_t __attribute__((ext_vector_type(4)));
typedef __bf16 bf16x8_t __attribute__((ext_vector_type(8)));
typedef float f32x4 __attribute__((ext_vector_type(4)));
typedef short short4_t __attribute__((ext_vector_type(4)));
typedef uint32_t u32;

static constexpr float QSCALE = 0.18033688011112042f;   // log2(e)/8 (folded into Wq,bq)

__device__ __forceinline__ void async16(void* lds, const void* g) {
  __builtin_amdgcn_global_load_lds(
      (const __attribute__((address_space(1))) void*)g,
      (__attribute__((address_space(3))) void*)lds, 16, 0, 0);
}

// ---------------------------------------------------------------- prep ----
__global__ __launch_bounds__(256) void prep_kernel(
    const float* __restrict__ x,
    const float* __restrict__ Wq, const float* __restrict__ Wk,
    const float* __restrict__ Wv, const float* __restrict__ Wo,
    const void* __restrict__ maskp,
    bf16* __restrict__ xb, bf16* __restrict__ WTall, bf16* __restrict__ WoT,
    u32* __restrict__ bmask)
{
  int bid = blockIdx.x;
  int tid = threadIdx.x;
  if (bid < 4096) {
    int idx = bid * 256 + tid;
    const float4* xf = (const float4*)x;
    float4 v = xf[idx];
    bf16x4_t o;
    o[0] = (bf16)v.x; o[1] = (bf16)v.y; o[2] = (bf16)v.z; o[3] = (bf16)v.w;
    ((bf16x4_t*)xb)[idx] = o;
  } else if (bid < 8192) {
    int gid = (bid - 4096) * 256 + tid;
    int sel = gid >> 18;
    int idx = gid & 262143;
    int n = idx >> 9, k = idx & 511;
    if (sel < 3) {
      const float* W = (sel == 0) ? Wq : (sel == 1) ? Wk : Wv;
      float v = W[k * 512 + n];
      if (sel == 0) v *= QSCALE;
      WTall[gid] = (bf16)v;
    } else {
      WoT[idx] = (bf16)Wo[k * 512 + n];
    }
  } else {
    int wid = (bid - 8192) * 256 + tid;   // 524,288 words
    const uint8_t* m8 = (const uint8_t*)maskp;
    bool u8mode = (__ballot(m8[4 * (tid & 63) + 1] != 0) != 0ull);
    int row = wid >> 7, wcol = wid & 127;
    size_t off = (size_t)row * 4096 + (size_t)wcol * 32;
    u32 w = 0;
    if (u8mode) {
      const uint4* p = (const uint4*)(m8 + off);
      uint4 a = p[0], b = p[1];
      u32 ws[8] = {a.x, a.y, a.z, a.w, b.x, b.y, b.z, b.w};
      #pragma unroll
      for (int j = 0; j < 32; ++j)
        if ((ws[j >> 2] >> ((j & 3) * 8)) & 0xffu) w |= (1u << j);
    } else {
      const uint4* p = (const uint4*)((const u32*)maskp + off);
      #pragma unroll
      for (int q = 0; q < 8; ++q) {
        uint4 a = p[q];
        if (a.x) w |= 1u << (q * 4 + 0);
        if (a.y) w |= 1u << (q * 4 + 1);
        if (a.z) w |= 1u << (q * 4 + 2);
        if (a.w) w |= 1u << (q * 4 + 3);
      }
    }
    bmask[((size_t)(row >> 6) * 64 + (wcol >> 1)) * 128 + (row & 63) * 2 + (wcol & 1)] = w;
  }
}

// ---------------------------------------------------------- QKV GEMM -------
// 128x128 tiles. C[8192 x 1536]; Q,K -> (B,H,T,64); V -> (B,H,64,T) via
// operand swap so V^T stores are lane-contiguous.
__global__ __launch_bounds__(256) void qkv_kernel(
    const bf16* __restrict__ xb, const bf16* __restrict__ WTall,
    const float* __restrict__ bq, const float* __restrict__ bk,
    const float* __restrict__ bv,
    bf16* __restrict__ Qb, bf16* __restrict__ Kb, bf16* __restrict__ Vtb)
{
  __shared__ char smem[32768];
  char* smX = smem;
  char* smW = smem + 16384;
  int tid = threadIdx.x;
  int lane = tid & 63, wave = tid >> 6;
  int lo = lane & 15, quad = lane >> 4;
  int wr = wave >> 1, wc = wave & 1;
  int bm = blockIdx.x * 128;
  int bn = blockIdx.y * 128;
  int sel = bn >> 9;   // 0=Q 1=K 2=V
  f32x4 acc[4][4] = {};
  for (int kc = 0; kc < 8; ++kc) {
    __syncthreads();
    for (int s = tid; s < 1024; s += 256) {
      int row = s >> 3, slot = s & 7, cg = slot ^ (row & 7);
      async16(smX + s * 16, xb + (size_t)(bm + row) * 512 + kc * 64 + cg * 8);
      async16(smW + s * 16, WTall + (size_t)(bn + row) * 512 + kc * 64 + cg * 8);
    }
    __syncthreads();
    #pragma unroll
    for (int ks = 0; ks < 2; ++ks) {
      bf16x8_t a[4], b[4];
      #pragma unroll
      for (int mt = 0; mt < 4; ++mt) {
        int row = wr * 64 + mt * 16 + lo;
        int ch = (ks * 4 + quad) ^ (row & 7);
        a[mt] = *(const bf16x8_t*)(smX + row * 128 + ch * 16);
      }
      #pragma unroll
      for (int nt = 0; nt < 4; ++nt) {
        int row = wc * 64 + nt * 16 + lo;
        int ch = (ks * 4 + quad) ^ (row & 7);
        b[nt] = *(const bf16x8_t*)(smW + row * 128 + ch * 16);
      }
      if (sel == 2) {
        #pragma unroll
        for (int mt = 0; mt < 4; ++mt)
          #pragma unroll
          for (int nt = 0; nt < 4; ++nt)
            acc[mt][nt] = __builtin_amdgcn_mfma_f32_16x16x32_bf16(
                b[nt], a[mt], acc[mt][nt], 0, 0, 0);
      } else {
        #pragma unroll
        for (int mt = 0; mt < 4; ++mt)
          #pragma unroll
          for (int nt = 0; nt < 4; ++nt)
            acc[mt][nt] = __builtin_amdgcn_mfma_f32_16x16x32_bf16(
                a[mt], b[nt], acc[mt][nt], 0, 0, 0);
      }
    }
  }
  int b_ = bm >> 12;
  if (sel < 2) {
    #pragma unroll
    for (int mt = 0; mt < 4; ++mt) {
      #pragma unroll
      for (int nt = 0; nt < 4; ++nt) {
        int n0 = (bn + wc * 64 + nt * 16 + lo) & 511;
        int h = n0 >> 6, dh = n0 & 63;
        int m0 = bm + wr * 64 + mt * 16 + quad * 4;
        int t0 = m0 & 4095;
        float bias = (sel == 0) ? QSCALE * bq[n0] : bk[n0];
        bf16* dst = (sel == 0 ? Qb : Kb) + (size_t)(b_ * H_ + h) * T_ * DH_ + dh;
        #pragma unroll
        for (int r = 0; r < 4; ++r)
          dst[(size_t)(t0 + r) * 64] = (bf16)(acc[mt][nt][r] + bias);
      }
    }
  } else {
    #pragma unroll
    for (int mt = 0; mt < 4; ++mt) {
      #pragma unroll
      for (int nt = 0; nt < 4; ++nt) {
        int t0 = (bm & 4095) + wr * 64 + mt * 16 + lo;
        #pragma unroll
        for (int r = 0; r < 4; ++r) {
          int n0 = (bn & 511) + wc * 64 + nt * 16 + quad * 4 + r;
          float v = acc[mt][nt][r] + bv[n0];
          Vtb[((size_t)(b_ * H_ + (n0 >> 6)) * DH_ + (n0 & 63)) * T_ + t0] = (bf16)v;
        }
      }
    }
  }
}

// ------------------------------------------------------ flash attention ----
// one WG per (b,h, 64-row q-tile); wave (qh,kh) = 32q x 32k.
// S^T = mfma(K,Q): C-layout (key=quad*4+r, q=lo) == A-frag of 16x16x16 MFMA,
// so P feeds PV directly from registers (no LDS round-trip).
__global__ __launch_bounds__(256, 4) void attn_kernel(
    const bf16* __restrict__ Qb, const bf16* __restrict__ Kb,
    const bf16* __restrict__ Vtb, const u32* __restrict__ bm2,
    bf16* __restrict__ Obuf)
{
  __shared__ char smem[16896];
  char* smK = smem;            // 8192 (64 key-rows x 128B, xor-swizzled)
  char* smV = smem + 8192;     // 8192 (64 d-rows x 128B, xor-swizzled)
  u32* smM = (u32*)(smem + 16384); // 512B mask words
  int tid = threadIdx.x;
  int lane = tid & 63, wave = tid >> 6;
  int lo = lane & 15, quad = lane >> 4;
  int qh = wave & 1, kh = wave >> 1;
  int bh = blockIdx.x >> 6;
  int qt64 = blockIdx.x & 63;
  int qbase = qt64 * 64;

  // preload Q fragments (loop-invariant); used as B operand of mfma(K,Q)
  const bf16* Qg = Qb + ((size_t)bh * T_ + qbase + qh * 32) * DH_;
  bf16x8_t qf[2][2];
  #pragma unroll
  for (int qt = 0; qt < 2; ++qt)
    #pragma unroll
    for (int ks = 0; ks < 2; ++ks)
      qf[qt][ks] = *(const bf16x8_t*)(Qg + (qt * 16 + lo) * 64 + ks * 32 + quad * 8);

  f32x4 O[2][4] = {};
  float lsum[2] = {0.f, 0.f};

  const bf16* Kg = Kb + (size_t)bh * T_ * DH_;
  const bf16* Vg = Vtb + (size_t)bh * DH_ * T_;
  const u32* mg = bm2 + (size_t)qt64 * 8192;

  for (int kc = 0; kc < 64; ++kc) {
    __syncthreads();
    for (int s = tid; s < 512; s += 256) {
      int row = s >> 3, slot = s & 7, cg = slot ^ (row & 7);
      async16(smK + s * 16, Kg + (size_t)(kc * 64 + row) * 64 + cg * 8);
      async16(smV + s * 16, Vg + (size_t)row * T_ + kc * 64 + cg * 8);
    }
    if (tid < 32) async16((char*)smM + tid * 16, mg + kc * 128 + tid * 4);
    __syncthreads();
    // S^T = K Q^T (32k x 32q per wave), tiles [kt][qt]
    f32x4 St[2][2] = {};
    #pragma unroll
    for (int ks = 0; ks < 2; ++ks)
      #pragma unroll
      for (int kt = 0; kt < 2; ++kt) {
        int krow = kh * 32 + kt * 16 + lo;
        int ch = (ks * 4 + quad) ^ (krow & 7);
        bf16x8_t kf = *(const bf16x8_t*)(smK + krow * 128 + ch * 16);
        #pragma unroll
        for (int qt = 0; qt < 2; ++qt)
          St[kt][qt] = __builtin_amdgcn_mfma_f32_16x16x32_bf16(
              kf, qf[qt][ks], St[kt][qt], 0, 0, 0);
      }
    // mask + exp2 + pack into PV A-fragments (registers only)
    short4_t pf[2][2];   // [qt][kt]
    #pragma unroll
    for (int qt = 0; qt < 2; ++qt) {
      u32 w = smM[(qh * 32 + qt * 16 + lo) * 2 + kh] >> (quad * 4);
      #pragma unroll
      for (int kt = 0; kt < 2; ++kt) {
        bf16x4_t t;
        #pragma unroll
        for (int r = 0; r < 4; ++r) {
          float p = ((w >> (kt * 16 + r)) & 1u)
                        ? __builtin_amdgcn_exp2f(St[kt][qt][r]) : 0.0f;
          lsum[qt] += p;
          t[r] = (bf16)p;
        }
        pf[qt][kt] = __builtin_bit_cast(short4_t, t);
      }
    }
    // O += P V via 16x16x16 MFMA; V B-frag = ds_read_b64 from swizzled V^T
    #pragma unroll
    for (int dt = 0; dt < 4; ++dt) {
      int d = dt * 16 + lo;
      #pragma unroll
      for (int kt = 0; kt < 2; ++kt) {
        int c0 = kh * 4 + kt * 2 + (quad >> 1);
        short4_t vf = *(const short4_t*)(
            smV + d * 128 + ((c0 ^ (d & 7)) << 4) + ((quad & 1) << 3));
        #pragma unroll
        for (int qt = 0; qt < 2; ++qt)
          O[qt][dt] = __builtin_amdgcn_mfma_f32_16x16x16bf16_1k(
              pf[qt][kt], vf, O[qt][dt], 0, 0, 0);
      }
    }
  }
  // ---- epilogue ----
  // lsum is per (qt): row q = qt*16+lo, keys split across quads -> reduce
  #pragma unroll
  for (int qt = 0; qt < 2; ++qt) {
    float v = lsum[qt];
    v += __shfl_xor(v, 16);
    v += __shfl_xor(v, 32);
    lsum[qt] = v;
  }
  __syncthreads();                 // done with smK/smV: reuse for combine
  float* smO = (float*)smem;       // 64 x 64 f32 = 16 KB
  float* smL = (float*)(smem + 16384); // 256 B
  if (kh == 1) {
    #pragma unroll
    for (int qt = 0; qt < 2; ++qt) {
      #pragma unroll
      for (int dt = 0; dt < 4; ++dt)
        #pragma unroll
        for (int r = 0; r < 4; ++r)
          smO[(qh * 32 + qt * 16 + quad * 4 + r) * 64 + dt * 16 + lo] = O[qt][dt][r];
      if (quad == 0) smL[qh * 32 + qt * 16 + lo] = lsum[qt];
    }
  }
  __syncthreads();
  if (kh == 0 && quad == 0) {
    #pragma unroll
    for (int qt = 0; qt < 2; ++qt)
      smL[qh * 32 + qt * 16 + lo] += lsum[qt];
  }
  __syncthreads();
  if (kh == 0) {
    bf16* Og = Obuf + ((size_t)bh * T_ + qbase + qh * 32) * DH_;
    #pragma unroll
    for (int qt = 0; qt < 2; ++qt) {
      #pragma unroll
      for (int r = 0; r < 4; ++r) {
        int rl = qt * 16 + quad * 4 + r;
        float inv = 1.0f / smL[qh * 32 + rl];
        #pragma unroll
        for (int dt = 0; dt < 4; ++dt) {
          float o = (O[qt][dt][r] + smO[(qh * 32 + rl) * 64 + dt * 16 + lo]) * inv;
          Og[(size_t)rl * 64 + dt * 16 + lo] = (bf16)o;
        }
      }
    }
  }
}

// ------------------------------------------------------ output proj --------
__global__ __launch_bounds__(256) void proj_kernel(
    const bf16* __restrict__ Obuf, const bf16* __restrict__ WoT,
    const float* __restrict__ bo, float* __restrict__ out)
{
  __shared__ char smem[32768];
  char* smA = smem;
  char* smW = smem + 16384;
  int tid = threadIdx.x;
  int lane = tid & 63, wave = tid >> 6;
  int lo = lane & 15, quad = lane >> 4;
  int wr = wave >> 1, wc = wave & 1;
  int bm = blockIdx.x * 128;
  int bn = blockIdx.y * 128;
  int b_ = bm >> 12, trow = bm & 4095;
  f32x4 acc[4][4] = {};
  for (int kc = 0; kc < 8; ++kc) {
    __syncthreads();
    const bf16* Ag = Obuf + ((size_t)(b_ * H_ + kc) * T_ + trow) * DH_;
    for (int s = tid; s < 1024; s += 256) {
      int row = s >> 3, slot = s & 7, cg = slot ^ (row & 7);
      async16(smA + s * 16, Ag + row * 64 + cg * 8);
      async16(smW + s * 16, WoT + (size_t)(bn + row) * 512 + kc * 64 + cg * 8);
    }
    __syncthreads();
    #pragma unroll
    for (int ks = 0; ks < 2; ++ks) {
      bf16x8_t a[4], b[4];
      #pragma unroll
      for (int mt = 0; mt < 4; ++mt) {
        int row = wr * 64 + mt * 16 + lo;
        int ch = (ks * 4 + quad) ^ (row & 7);
        a[mt] = *(const bf16x8_t*)(smA + row * 128 + ch * 16);
      }
      #pragma unroll
      for (int nt = 0; nt < 4; ++nt) {
        int row = wc * 64 + nt * 16 + lo;
        int ch = (ks * 4 + quad) ^ (row & 7);
        b[nt] = *(const bf16x8_t*)(smW + row * 128 + ch * 16);
      }
      #pragma unroll
      for (int mt = 0; mt < 4; ++mt)
        #pragma unroll
        for (int nt = 0; nt < 4; ++nt)
          acc[mt][nt] = __builtin_amdgcn_mfma_f32_16x16x32_bf16(
              a[mt], b[nt], acc[mt][nt], 0, 0, 0);
    }
  }
  #pragma unroll
  for (int mt = 0; mt < 4; ++mt) {
    #pragma unroll
    for (int nt = 0; nt < 4; ++nt) {
      int n_g = bn + wc * 64 + nt * 16 + lo;
      int m0 = bm + wr * 64 + mt * 16 + quad * 4;
      float bias = bo[n_g];
      #pragma unroll
      for (int r = 0; r < 4; ++r)
        out[(size_t)(m0 + r) * 512 + n_g] = acc[mt][nt][r] + bias;
    }
  }
}

// --------------------------------------------------------------- launch ----
extern "C" void kernel_launch(void* const* d_in, const int* in_sizes, int n_in,
                              void* d_out, int out_size, void* d_ws, size_t ws_size,
                              hipStream_t stream) {
  const float* x  = (const float*)d_in[0];
  const float* Wq = (const float*)d_in[1];
  const float* bq = (const float*)d_in[2];
  const float* Wk = (const float*)d_in[3];
  const float* bk = (const float*)d_in[4];
  const float* Wv = (const float*)d_in[5];
  const float* bv = (const float*)d_in[6];
  const float* Wo = (const float*)d_in[7];
  const float* bo = (const float*)d_in[8];
  const void* maskp = d_in[9];
  float* out = (float*)d_out;

  char* w = (char*)d_ws;
  bf16* xb    = (bf16*)(w);              //  8,388,608 B
  bf16* WTall = (bf16*)(w + 8388608);    //  1,572,864 B
  bf16* WoT   = (bf16*)(w + 9961472);    //    524,288 B
  bf16* Qb    = (bf16*)(w + 10485760);   //  8,388,608 B
  bf16* Kb    = (bf16*)(w + 18874368);   //  8,388,608 B
  bf16* Vtb   = (bf16*)(w + 27262976);   //  8,388,608 B  (B,H,DH,T)
  bf16* Obuf  = (bf16*)(w + 35651584);   //  8,388,608 B
  u32*  bmask = (u32*)(w + 44040192);    //  2,097,152 B

  prep_kernel<<<10240, 256, 0, stream>>>(x, Wq, Wk, Wv, Wo, maskp,
                                         xb, WTall, WoT, bmask);
  qkv_kernel<<<dim3(64, 12), 256, 0, stream>>>(xb, WTall, bq, bk, bv,
                                               Qb, Kb, Vtb);
  attn_kernel<<<1024, 256, 0, stream>>>(Qb, Kb, Vtb, bmask, Obuf);
  proj_kernel<<<dim3(64, 4), 256, 0, stream>>>(Obuf, WoT, bo, out);
}

// Round 4
// 296.036 us; speedup vs baseline: 1.4606x; 1.0201x over previous
//
#include <hip/hip_runtime.h>
#include <stdint.h>

#define B_ 2
#define T_ 4096
#define D_ 512
#define H_ 8
#define DH_ 64

typedef __bf16 bf16;
typedef __bf16 bf16x4_t __attribute__((ext_vector_type(4)));
typedef __bf16 bf16x8_t __attribute__((ext_vector_type(8)));
typedef float f32x4 __attribute__((ext_vector_type(4)));
typedef short short4_t __attribute__((ext_vector_type(4)));
typedef uint32_t u32;

static constexpr float QSCALE = 0.18033688011112042f;   // log2(e)/8 (folded into Wq,bq)

__device__ __forceinline__ void async16(void* lds, const void* g) {
  __builtin_amdgcn_global_load_lds(
      (const __attribute__((address_space(1))) void*)g,
      (__attribute__((address_space(3))) void*)lds, 16, 0, 0);
}

// ---------------------------------------------------------------- prep ----
__global__ __launch_bounds__(256) void prep_kernel(
    const float* __restrict__ x,
    const float* __restrict__ Wq, const float* __restrict__ Wk,
    const float* __restrict__ Wv, const float* __restrict__ Wo,
    const void* __restrict__ maskp,
    bf16* __restrict__ xb, bf16* __restrict__ WTall, bf16* __restrict__ WoT,
    u32* __restrict__ bmask)
{
  int bid = blockIdx.x;
  int tid = threadIdx.x;
  if (bid < 4096) {
    int idx = bid * 256 + tid;
    const float4* xf = (const float4*)x;
    float4 v = xf[idx];
    bf16x4_t o;
    o[0] = (bf16)v.x; o[1] = (bf16)v.y; o[2] = (bf16)v.z; o[3] = (bf16)v.w;
    ((bf16x4_t*)xb)[idx] = o;
  } else if (bid < 8192) {
    int gid = (bid - 4096) * 256 + tid;
    int sel = gid >> 18;
    int idx = gid & 262143;
    int n = idx >> 9, k = idx & 511;
    if (sel < 3) {
      const float* W = (sel == 0) ? Wq : (sel == 1) ? Wk : Wv;
      float v = W[k * 512 + n];
      if (sel == 0) v *= QSCALE;
      WTall[gid] = (bf16)v;
    } else {
      WoT[idx] = (bf16)Wo[k * 512 + n];
    }
  } else {
    int wid = (bid - 8192) * 256 + tid;   // 524,288 words
    const uint8_t* m8 = (const uint8_t*)maskp;
    bool u8mode = (__ballot(m8[4 * (tid & 63) + 1] != 0) != 0ull);
    int row = wid >> 7, wcol = wid & 127;
    size_t off = (size_t)row * 4096 + (size_t)wcol * 32;
    u32 w = 0;
    if (u8mode) {
      const uint4* p = (const uint4*)(m8 + off);
      uint4 a = p[0], b = p[1];
      u32 ws[8] = {a.x, a.y, a.z, a.w, b.x, b.y, b.z, b.w};
      #pragma unroll
      for (int j = 0; j < 32; ++j)
        if ((ws[j >> 2] >> ((j & 3) * 8)) & 0xffu) w |= (1u << j);
    } else {
      const uint4* p = (const uint4*)((const u32*)maskp + off);
      #pragma unroll
      for (int q = 0; q < 8; ++q) {
        uint4 a = p[q];
        if (a.x) w |= 1u << (q * 4 + 0);
        if (a.y) w |= 1u << (q * 4 + 1);
        if (a.z) w |= 1u << (q * 4 + 2);
        if (a.w) w |= 1u << (q * 4 + 3);
      }
    }
    bmask[((size_t)(row >> 6) * 64 + (wcol >> 1)) * 128 + (row & 63) * 2 + (wcol & 1)] = w;
  }
}

// ---------------------------------------------------------- QKV GEMM -------
// 128x128 tiles. Q,K computed operand-SWAPPED (D rows = W-dim) so each lane
// holds 4 consecutive dh for one t -> 8-B stores into (B,H,T,64).
// V computed NORMAL (D rows = t) so each lane holds 4 consecutive t for one
// dh -> 8-B stores into (B,H,64,T).
__global__ __launch_bounds__(256) void qkv_kernel(
    const bf16* __restrict__ xb, const bf16* __restrict__ WTall,
    const float* __restrict__ bq, const float* __restrict__ bk,
    const float* __restrict__ bv,
    bf16* __restrict__ Qb, bf16* __restrict__ Kb, bf16* __restrict__ Vtb)
{
  __shared__ char smem[32768];
  char* smX = smem;
  char* smW = smem + 16384;
  int tid = threadIdx.x;
  int lane = tid & 63, wave = tid >> 6;
  int lo = lane & 15, quad = lane >> 4;
  int wr = wave >> 1, wc = wave & 1;
  int bm = blockIdx.x * 128;
  int bn = blockIdx.y * 128;
  int sel = bn >> 9;   // 0=Q 1=K 2=V
  f32x4 acc[4][4] = {};
  for (int kc = 0; kc < 8; ++kc) {
    __syncthreads();
    for (int s = tid; s < 1024; s += 256) {
      int row = s >> 3, slot = s & 7, cg = slot ^ (row & 7);
      async16(smX + s * 16, xb + (size_t)(bm + row) * 512 + kc * 64 + cg * 8);
      async16(smW + s * 16, WTall + (size_t)(bn + row) * 512 + kc * 64 + cg * 8);
    }
    __syncthreads();
    #pragma unroll
    for (int ks = 0; ks < 2; ++ks) {
      bf16x8_t a[4], b[4];
      #pragma unroll
      for (int mt = 0; mt < 4; ++mt) {
        int row = wr * 64 + mt * 16 + lo;
        int ch = (ks * 4 + quad) ^ (row & 7);
        a[mt] = *(const bf16x8_t*)(smX + row * 128 + ch * 16);
      }
      #pragma unroll
      for (int nt = 0; nt < 4; ++nt) {
        int row = wc * 64 + nt * 16 + lo;
        int ch = (ks * 4 + quad) ^ (row & 7);
        b[nt] = *(const bf16x8_t*)(smW + row * 128 + ch * 16);
      }
      if (sel < 2) {
        #pragma unroll
        for (int mt = 0; mt < 4; ++mt)
          #pragma unroll
          for (int nt = 0; nt < 4; ++nt)
            acc[mt][nt] = __builtin_amdgcn_mfma_f32_16x16x32_bf16(
                b[nt], a[mt], acc[mt][nt], 0, 0, 0);   // D: m=W-row, n=t
      } else {
        #pragma unroll
        for (int mt = 0; mt < 4; ++mt)
          #pragma unroll
          for (int nt = 0; nt < 4; ++nt)
            acc[mt][nt] = __builtin_amdgcn_mfma_f32_16x16x32_bf16(
                a[mt], b[nt], acc[mt][nt], 0, 0, 0);   // D: m=t, n=W-row
      }
    }
  }
  int b_ = bm >> 12;
  if (sel < 2) {
    const float* bias = (sel == 0) ? bq : bk;
    bf16* base = (sel == 0) ? Qb : Kb;
    #pragma unroll
    for (int mt = 0; mt < 4; ++mt) {
      int t = (bm & 4095) + wr * 64 + mt * 16 + lo;
      #pragma unroll
      for (int nt = 0; nt < 4; ++nt) {
        int n0 = (bn + wc * 64 + nt * 16 + quad * 4) & 511;
        int h = n0 >> 6, dh0 = n0 & 63;
        bf16x4_t v;
        #pragma unroll
        for (int r = 0; r < 4; ++r) {
          float bs = bias[n0 + r];
          if (sel == 0) bs *= QSCALE;
          v[r] = (bf16)(acc[mt][nt][r] + bs);
        }
        *(bf16x4_t*)(base + (size_t)(b_ * H_ + h) * T_ * DH_ +
                     (size_t)t * 64 + dh0) = v;
      }
    }
  } else {
    #pragma unroll
    for (int nt = 0; nt < 4; ++nt) {
      int n0 = (bn + wc * 64 + nt * 16 + lo) & 511;
      int h = n0 >> 6, dh = n0 & 63;
      float bs = bv[n0];
      #pragma unroll
      for (int mt = 0; mt < 4; ++mt) {
        int t0 = (bm & 4095) + wr * 64 + mt * 16 + quad * 4;
        bf16x4_t v;
        #pragma unroll
        for (int r = 0; r < 4; ++r) v[r] = (bf16)(acc[mt][nt][r] + bs);
        *(bf16x4_t*)(Vtb + ((size_t)(b_ * H_ + h) * DH_ + dh) * T_ + t0) = v;
      }
    }
  }
}

// ------------------------------------------------------ flash attention ----
// one WG per (b,h, 64-row q-tile); wave (qh,kh) = 32q x 32k.
// S^T = mfma(K,Q); its C-layout == A-frag of 16x16x16 MFMA -> PV from regs.
// Row sums accumulated on the MFMA pipe via a ones-column B-fragment.
__global__ __launch_bounds__(256, 4) void attn_kernel(
    const bf16* __restrict__ Qb, const bf16* __restrict__ Kb,
    const bf16* __restrict__ Vtb, const u32* __restrict__ bm2,
    bf16* __restrict__ Obuf)
{
  __shared__ char smem[17408];
  char* smK = smem;            // 8192 (64 key-rows x 128B, xor-swizzled)
  char* smV = smem + 8192;     // 8192 (64 d-rows x 128B, xor-swizzled)
  u32* smM = (u32*)(smem + 16384);      // 512B mask words
  float* smLa = (float*)(smem + 16896); // 256B row-sum partials kh=0
  float* smLb = (float*)(smem + 17152); // 256B row-sum partials kh=1
  int tid = threadIdx.x;
  int lane = tid & 63, wave = tid >> 6;
  int lo = lane & 15, quad = lane >> 4;
  int qh = wave & 1, kh = wave >> 1;
  int bh = blockIdx.x >> 6;
  int qt64 = blockIdx.x & 63;
  int qbase = qt64 * 64;

  // preload Q fragments (loop-invariant); used as B operand of mfma(K,Q)
  const bf16* Qg = Qb + ((size_t)bh * T_ + qbase + qh * 32) * DH_;
  bf16x8_t qf[2][2];
  #pragma unroll
  for (int qt = 0; qt < 2; ++qt)
    #pragma unroll
    for (int ks = 0; ks < 2; ++ks)
      qf[qt][ks] = *(const bf16x8_t*)(Qg + (qt * 16 + lo) * 64 + ks * 32 + quad * 8);

  // ones-column B-frag for rowsum MFMA: B[k][0]=1, else 0
  short one = (lo == 0) ? (short)0x3F80 : (short)0;
  short4_t ones = {one, one, one, one};

  f32x4 O[2][4] = {};
  f32x4 Ol[2] = {};   // rowsum accumulators (col 0 meaningful)

  const bf16* Kg = Kb + (size_t)bh * T_ * DH_;
  const bf16* Vg = Vtb + (size_t)bh * DH_ * T_;
  const u32* mg = bm2 + (size_t)qt64 * 8192;

  for (int kc = 0; kc < 64; ++kc) {
    __syncthreads();
    for (int s = tid; s < 512; s += 256) {
      int row = s >> 3, slot = s & 7, cg = slot ^ (row & 7);
      async16(smK + s * 16, Kg + (size_t)(kc * 64 + row) * 64 + cg * 8);
      async16(smV + s * 16, Vg + (size_t)row * T_ + kc * 64 + cg * 8);
    }
    if (tid < 32) async16((char*)smM + tid * 16, mg + kc * 128 + tid * 4);
    __syncthreads();
    // S^T = K Q^T (32k x 32q per wave), tiles [kt][qt]
    f32x4 St[2][2] = {};
    #pragma unroll
    for (int ks = 0; ks < 2; ++ks)
      #pragma unroll
      for (int kt = 0; kt < 2; ++kt) {
        int krow = kh * 32 + kt * 16 + lo;
        int ch = (ks * 4 + quad) ^ (krow & 7);
        bf16x8_t kf = *(const bf16x8_t*)(smK + krow * 128 + ch * 16);
        #pragma unroll
        for (int qt = 0; qt < 2; ++qt)
          St[kt][qt] = __builtin_amdgcn_mfma_f32_16x16x32_bf16(
              kf, qf[qt][ks], St[kt][qt], 0, 0, 0);
      }
    // mask (sign-extended bitfield + AND) + exp2 + pack to PV A-frags
    short4_t pf[2][2];   // [qt][kt]
    #pragma unroll
    for (int qt = 0; qt < 2; ++qt) {
      u32 w = smM[(qh * 32 + qt * 16 + lo) * 2 + kh] >> (quad * 4);
      #pragma unroll
      for (int kt = 0; kt < 2; ++kt) {
        bf16x4_t t;
        #pragma unroll
        for (int r = 0; r < 4; ++r) {
          int mb = ((int)(w << (31 - (kt * 16 + r)))) >> 31;  // v_bfe_i32
          u32 pe = __builtin_bit_cast(u32, __builtin_amdgcn_exp2f(St[kt][qt][r]));
          t[r] = __builtin_bit_cast(bf16,
                   (unsigned short)(__builtin_bit_cast(float, pe & (u32)mb) == 0.f
                        ? 0 : 0));  // placeholder (see below)
          t[r] = (bf16)__builtin_bit_cast(float, pe & (u32)mb);
        }
        pf[qt][kt] = __builtin_bit_cast(short4_t, t);
      }
    }
    // O += P V via 16x16x16 MFMA; rowsum via ones-column
    #pragma unroll
    for (int kt = 0; kt < 2; ++kt)
      #pragma unroll
      for (int qt = 0; qt < 2; ++qt)
        Ol[qt] = __builtin_amdgcn_mfma_f32_16x16x16bf16_1k(
            pf[qt][kt], ones, Ol[qt], 0, 0, 0);
    #pragma unroll
    for (int dt = 0; dt < 4; ++dt) {
      int d = dt * 16 + lo;
      #pragma unroll
      for (int kt = 0; kt < 2; ++kt) {
        int c0 = kh * 4 + kt * 2 + (quad >> 1);
        short4_t vf = *(const short4_t*)(
            smV + d * 128 + ((c0 ^ (d & 7)) << 4) + ((quad & 1) << 3));
        #pragma unroll
        for (int qt = 0; qt < 2; ++qt)
          O[qt][dt] = __builtin_amdgcn_mfma_f32_16x16x16bf16_1k(
              pf[qt][kt], vf, O[qt][dt], 0, 0, 0);
      }
    }
  }
  // ---- epilogue: rowsums live in lanes lo==0 of Ol; combine kh pair ----
  __syncthreads();                 // done with smK/smV: reuse for combine
  float* smO = (float*)smem;       // 64 x 64 f32 = 16 KB
  if (lo == 0) {
    float* dst = (kh == 0) ? smLa : smLb;
    #pragma unroll
    for (int qt = 0; qt < 2; ++qt)
      #pragma unroll
      for (int r = 0; r < 4; ++r)
        dst[qh * 32 + qt * 16 + quad * 4 + r] = Ol[qt][r];
  }
  if (kh == 1) {
    #pragma unroll
    for (int qt = 0; qt < 2; ++qt)
      #pragma unroll
      for (int dt = 0; dt < 4; ++dt)
        #pragma unroll
        for (int r = 0; r < 4; ++r)
          smO[(qh * 32 + qt * 16 + quad * 4 + r) * 64 + dt * 16 + lo] = O[qt][dt][r];
  }
  __syncthreads();
  if (kh == 0) {
    bf16* Og = Obuf + ((size_t)bh * T_ + qbase + qh * 32) * DH_;
    #pragma unroll
    for (int qt = 0; qt < 2; ++qt) {
      #pragma unroll
      for (int r = 0; r < 4; ++r) {
        int rl = qt * 16 + quad * 4 + r;
        float inv = 1.0f / (smLa[qh * 32 + rl] + smLb[qh * 32 + rl]);
        #pragma unroll
        for (int dt = 0; dt < 4; ++dt) {
          float o = (O[qt][dt][r] + smO[(qh * 32 + rl) * 64 + dt * 16 + lo]) * inv;
          Og[(size_t)rl * 64 + dt * 16 + lo] = (bf16)o;
        }
      }
    }
  }
}

// ------------------------------------------------------ output proj --------
// operand-swapped: D rows = out-col -> each lane holds 4 consecutive cols
// for one t -> float4 stores.
__global__ __launch_bounds__(256) void proj_kernel(
    const bf16* __restrict__ Obuf, const bf16* __restrict__ WoT,
    const float* __restrict__ bo, float* __restrict__ out)
{
  __shared__ char smem[32768];
  char* smA = smem;
  char* smW = smem + 16384;
  int tid = threadIdx.x;
  int lane = tid & 63, wave = tid >> 6;
  int lo = lane & 15, quad = lane >> 4;
  int wr = wave >> 1, wc = wave & 1;
  int bm = blockIdx.x * 128;
  int bn = blockIdx.y * 128;
  int b_ = bm >> 12, trow = bm & 4095;
  f32x4 acc[4][4] = {};
  for (int kc = 0; kc < 8; ++kc) {
    __syncthreads();
    const bf16* Ag = Obuf + ((size_t)(b_ * H_ + kc) * T_ + trow) * DH_;
    for (int s = tid; s < 1024; s += 256) {
      int row = s >> 3, slot = s & 7, cg = slot ^ (row & 7);
      async16(smA + s * 16, Ag + row * 64 + cg * 8);
      async16(smW + s * 16, WoT + (size_t)(bn + row) * 512 + kc * 64 + cg * 8);
    }
    __syncthreads();
    #pragma unroll
    for (int ks = 0; ks < 2; ++ks) {
      bf16x8_t a[4], b[4];
      #pragma unroll
      for (int mt = 0; mt < 4; ++mt) {
        int row = wr * 64 + mt * 16 + lo;
        int ch = (ks * 4 + quad) ^ (row & 7);
        a[mt] = *(const bf16x8_t*)(smA + row * 128 + ch * 16);
      }
      #pragma unroll
      for (int nt = 0; nt < 4; ++nt) {
        int row = wc * 64 + nt * 16 + lo;
        int ch = (ks * 4 + quad) ^ (row & 7);
        b[nt] = *(const bf16x8_t*)(smW + row * 128 + ch * 16);
      }
      #pragma unroll
      for (int mt = 0; mt < 4; ++mt)
        #pragma unroll
        for (int nt = 0; nt < 4; ++nt)
          acc[mt][nt] = __builtin_amdgcn_mfma_f32_16x16x32_bf16(
              b[nt], a[mt], acc[mt][nt], 0, 0, 0);   // D: m=out-col, n=t
    }
  }
  #pragma unroll
  for (int mt = 0; mt < 4; ++mt) {
    int t = bm + wr * 64 + mt * 16 + lo;
    #pragma unroll
    for (int nt = 0; nt < 4; ++nt) {
      int c0 = bn + wc * 64 + nt * 16 + quad * 4;
      float4 v;
      v.x = acc[mt][nt][0] + bo[c0 + 0];
      v.y = acc[mt][nt][1] + bo[c0 + 1];
      v.z = acc[mt][nt][2] + bo[c0 + 2];
      v.w = acc[mt][nt][3] + bo[c0 + 3];
      *(float4*)(out + (size_t)t * 512 + c0) = v;
    }
  }
}

// --------------------------------------------------------------- launch ----
extern "C" void kernel_launch(void* const* d_in, const int* in_sizes, int n_in,
                              void* d_out, int out_size, void* d_ws, size_t ws_size,
                              hipStream_t stream) {
  const float* x  = (const float*)d_in[0];
  const float* Wq = (const float*)d_in[1];
  const float* bq = (const float*)d_in[2];
  const float* Wk = (const float*)d_in[3];
  const float* bk = (const float*)d_in[4];
  const float* Wv = (const float*)d_in[5];
  const float* bv = (const float*)d_in[6];
  const float* Wo = (const float*)d_in[7];
  const float* bo = (const float*)d_in[8];
  const void* maskp = d_in[9];
  float* out = (float*)d_out;

  char* w = (char*)d_ws;
  bf16* xb    = (bf16*)(w);              //  8,388,608 B
  bf16* WTall = (bf16*)(w + 8388608);    //  1,572,864 B
  bf16* WoT   = (bf16*)(w + 9961472);    //    524,288 B
  bf16* Qb    = (bf16*)(w + 10485760);   //  8,388,608 B
  bf16* Kb    = (bf16*)(w + 18874368);   //  8,388,608 B
  bf16* Vtb   = (bf16*)(w + 27262976);   //  8,388,608 B  (B,H,DH,T)
  bf16* Obuf  = (bf16*)(w + 35651584);   //  8,388,608 B
  u32*  bmask = (u32*)(w + 44040192);    //  2,097,152 B

  prep_kernel<<<10240, 256, 0, stream>>>(x, Wq, Wk, Wv, Wo, maskp,
                                         xb, WTall, WoT, bmask);
  qkv_kernel<<<dim3(64, 12), 256, 0, stream>>>(xb, WTall, bq, bk, bv,
                                               Qb, Kb, Vtb);
  attn_kernel<<<1024, 256, 0, stream>>>(Qb, Kb, Vtb, bmask, Obuf);
  proj_kernel<<<dim3(64, 4), 256, 0, stream>>>(Obuf, WoT, bo, out);
}